// Round 14
// baseline (503.506 us; speedup 1.0000x reference)
//
#include <hip/hip_runtime.h>
#include <hip/hip_bf16.h>
#include <math.h>

// Round 14: 3-kernel split.
//  r13 monolith (427us): hero chain MFMA'd, but C/E/F VALU phases +24
//  barriers + 32KB arena cap occupancy at 40%, VGPR 64 + residual spill.
//  Intermediates are tiny (ho 21MB bf16, g 2MB f32 => ~8us HBM round trip)
//  so split:
//   K1 hero MFMA chain -> ho (LDS 19.2KB, ~8 wg/CU, stream-bound)
//   K2 uv + 50-pair counter + pool -> g (all lanes on pairs)
//   K3 team + final MLP -> out (64 rows x 4 lanes = all 256 lanes)

#define NB 65536
#define SPB 24          // K1/K2
#define SPB3 32         // K3

typedef __attribute__((ext_vector_type(8))) short short8;
typedef __attribute__((ext_vector_type(4))) float f32x4;

__device__ __forceinline__ unsigned bfr(float f) {
    unsigned u = __float_as_uint(f);
    return (u + 0x7fffu + ((u >> 16) & 1u)) >> 16;
}
__device__ __forceinline__ unsigned pack_bf(float a, float b) {
    return bfr(a) | (bfr(b) << 16);
}
__device__ __forceinline__ float bf_lo(unsigned u) { return __uint_as_float(u << 16); }
__device__ __forceinline__ float bf_hi(unsigned u) { return __uint_as_float(u & 0xffff0000u); }

// ================= K1: hero chain (140->32->32->16), MFMA ==================
__global__ __launch_bounds__(256, 4) void k1_hero(
    const float* __restrict__ x,
    const float* __restrict__ h_w1, const float* __restrict__ h_b1,
    const float* __restrict__ h_w2, const float* __restrict__ h_b2,
    const float* __restrict__ h_w3, const float* __restrict__ h_b3,
    unsigned* __restrict__ ho_ws)      // [NB*10][8] u32 (16 bf16/row)
{
    __shared__ unsigned smem_u[4800];            // 19.2 KB: acts [240][40] u16
    unsigned short* const acts = (unsigned short*)smem_u;

    const int tid = threadIdx.x;
    const int s0  = blockIdx.x * SPB;
    const int vs  = (NB - s0 < SPB) ? (NB - s0) : SPB;
    const int vr  = vs * 10;

    const int lane = tid & 63;
    const int wv   = tid >> 6;
    const int lm   = lane & 15;
    const int lg   = lane >> 4;
    const short8 zero8 = (short8){0,0,0,0,0,0,0,0};

    // ---- L1: [240x140]@[140x32], rolled K-chunks, JIT B-frags ----
    f32x4 acc[4][2];
    #pragma unroll
    for (int t = 0; t < 4; ++t) {
        const float b0 = h_b1[lm], b1 = h_b1[16 + lm];
        acc[t][0] = (f32x4){b0, b0, b0, b0};
        acc[t][1] = (f32x4){b1, b1, b1, b1};
    }
    for (int c = 0; c < 5; ++c) {
        short8 w0f, w1f;
        #pragma unroll
        for (int i = 0; i < 8; ++i) {
            const int k = c * 32 + lg * 8 + i;
            w0f[i] = (short)((k < 140) ? bfr(h_w1[k * 32 + lm]) : 0);
            w1f[i] = (short)((k < 140) ? bfr(h_w1[k * 32 + 16 + lm]) : 0);
        }
        for (int j = tid; j < vr * 8; j += 256) {
            const int row = j >> 3, q = j & 7;
            unsigned lo = 0, hi = 0;
            if (c < 4 || q < 3) {
                const float4 v = *(const float4*)(
                    x + ((size_t)s0 * 10 + row) * 140 + c * 32 + q * 4);
                lo = pack_bf(v.x, v.y);
                hi = pack_bf(v.z, v.w);
            }
            smem_u[row * 20 + q * 2]     = lo;
            smem_u[row * 20 + q * 2 + 1] = hi;
        }
        __syncthreads();
        #pragma unroll
        for (int t = 0; t < 4; ++t) {
            const int tl = wv + 4 * t;
            if (tl < 15) {
                const short8 af = *(const short8*)(acts + (tl * 16 + lm) * 40 + lg * 8);
                acc[t][0] = __builtin_amdgcn_mfma_f32_16x16x32_bf16(af, w0f, acc[t][0], 0, 0, 0);
                acc[t][1] = __builtin_amdgcn_mfma_f32_16x16x32_bf16(af, w1f, acc[t][1], 0, 0, 0);
            }
        }
        __syncthreads();
    }
    #pragma unroll
    for (int t = 0; t < 4; ++t) {
        const int tl = wv + 4 * t;
        if (tl < 15) {
            #pragma unroll
            for (int nt = 0; nt < 2; ++nt)
                #pragma unroll
                for (int r = 0; r < 4; ++r)
                    acts[(tl * 16 + lg * 4 + r) * 40 + nt * 16 + lm] =
                        (unsigned short)bfr(fmaxf(acc[t][nt][r], 0.f));
        }
    }
    __syncthreads();

    // ---- L2: [240x32]@[32x32], in-place ----
    {
        short8 af[4];
        #pragma unroll
        for (int t = 0; t < 4; ++t) {
            const int tl = wv + 4 * t;
            af[t] = (tl < 15) ? *(const short8*)(acts + (tl * 16 + lm) * 40 + lg * 8) : zero8;
        }
        short8 w0f, w1f;
        #pragma unroll
        for (int i = 0; i < 8; ++i) {
            const int k = lg * 8 + i;
            w0f[i] = (short)bfr(h_w2[k * 32 + lm]);
            w1f[i] = (short)bfr(h_w2[k * 32 + 16 + lm]);
        }
        __syncthreads();
        #pragma unroll
        for (int t = 0; t < 4; ++t) {
            const float b0 = h_b2[lm], b1 = h_b2[16 + lm];
            f32x4 a20 = (f32x4){b0, b0, b0, b0};
            f32x4 a21 = (f32x4){b1, b1, b1, b1};
            const int tl = wv + 4 * t;
            if (tl < 15) {
                a20 = __builtin_amdgcn_mfma_f32_16x16x32_bf16(af[t], w0f, a20, 0, 0, 0);
                a21 = __builtin_amdgcn_mfma_f32_16x16x32_bf16(af[t], w1f, a21, 0, 0, 0);
                #pragma unroll
                for (int r = 0; r < 4; ++r) {
                    acts[(tl * 16 + lg * 4 + r) * 40 + lm]      =
                        (unsigned short)bfr(fmaxf(a20[r], 0.f));
                    acts[(tl * 16 + lg * 4 + r) * 40 + 16 + lm] =
                        (unsigned short)bfr(fmaxf(a21[r], 0.f));
                }
            }
        }
        __syncthreads();
    }

    // ---- L3: [240x32]@[32x16] (linear) -> acts cols 0..15 ----
    {
        short8 af[4];
        #pragma unroll
        for (int t = 0; t < 4; ++t) {
            const int tl = wv + 4 * t;
            af[t] = (tl < 15) ? *(const short8*)(acts + (tl * 16 + lm) * 40 + lg * 8) : zero8;
        }
        short8 w3f;
        #pragma unroll
        for (int i = 0; i < 8; ++i)
            w3f[i] = (short)bfr(h_w3[(lg * 8 + i) * 16 + lm]);
        __syncthreads();
        #pragma unroll
        for (int t = 0; t < 4; ++t) {
            const float b = h_b3[lm];
            f32x4 a3 = (f32x4){b, b, b, b};
            const int tl = wv + 4 * t;
            if (tl < 15) {
                a3 = __builtin_amdgcn_mfma_f32_16x16x32_bf16(af[t], w3f, a3, 0, 0, 0);
                #pragma unroll
                for (int r = 0; r < 4; ++r)
                    acts[(tl * 16 + lg * 4 + r) * 40 + lm] = (unsigned short)bfr(a3[r]);
            }
        }
        __syncthreads();
    }

    // ---- coalesced ho writeback: [vr][8] u32 ----
    for (int j = tid; j < vr * 8; j += 256) {
        const int row = j >> 3, q = j & 7;
        ho_ws[((size_t)s0 * 10 + row) * 8 + q] = smem_u[row * 20 + q];
    }
}

// ================= K2: uv + counter pairs + pool -> g ==================
__global__ __launch_bounds__(256, 4) void k2_counter(
    const unsigned* __restrict__ ho_ws,
    const float* __restrict__ c_w1, const float* __restrict__ c_b1,
    const float* __restrict__ c_w2, const float* __restrict__ c_b2,
    const float* __restrict__ c_w3, const float* __restrict__ c_b3,
    float* __restrict__ g_ws)          // [NB][8] f32
{
    __shared__ unsigned smem_u[5040];  // hX [240][17]=4080 | sPm 960 f32
    unsigned* const hX  = smem_u;
    float*    const sPm = (float*)(smem_u + 4080);

    const int tid = threadIdx.x;
    const int s0  = blockIdx.x * SPB;
    const int vs  = (NB - s0 < SPB) ? (NB - s0) : SPB;
    const int vr  = vs * 10;

    // ---- uv: lane owns row; coalesced 32B ho read; full-unroll 16x32 ----
    if (tid < vr) {
        const uint4 p0 = *(const uint4*)(ho_ws + ((size_t)s0 * 10 + tid) * 8);
        const uint4 p1 = *(const uint4*)(ho_ws + ((size_t)s0 * 10 + tid) * 8 + 4);
        float ho[16];
        ho[0] = bf_lo(p0.x); ho[1] = bf_hi(p0.x); ho[2] = bf_lo(p0.y); ho[3] = bf_hi(p0.y);
        ho[4] = bf_lo(p0.z); ho[5] = bf_hi(p0.z); ho[6] = bf_lo(p0.w); ho[7] = bf_hi(p0.w);
        ho[8] = bf_lo(p1.x); ho[9] = bf_hi(p1.x); ho[10] = bf_lo(p1.y); ho[11] = bf_hi(p1.y);
        ho[12] = bf_lo(p1.z); ho[13] = bf_hi(p1.z); ho[14] = bf_lo(p1.w); ho[15] = bf_hi(p1.w);
        float u[16], v[16];
        #pragma unroll
        for (int o = 0; o < 16; ++o) { u[o] = 0.f; v[o] = 0.f; }
        #pragma unroll
        for (int k = 0; k < 16; ++k) {
            const float hk = ho[k];
            const float* wu = c_w1 + k * 16;
            const float* wv = c_w1 + (16 + k) * 16;
            #pragma unroll
            for (int o = 0; o < 16; ++o) {
                u[o] = fmaf(hk, wu[o], u[o]);
                v[o] = fmaf(hk, wv[o], v[o]);
            }
        }
        #pragma unroll
        for (int cc = 0; cc < 8; ++cc) {
            hX[tid * 17 + cc]     = pack_bf(u[2 * cc], u[2 * cc + 1]);
            hX[tid * 17 + 8 + cc] = pack_bf(v[2 * cc], v[2 * cc + 1]);
        }
    }
    __syncthreads();

    // ---- 50 pairs/sample, counter L2/L3 + pool2, 10 lanes/sample ----
    if (tid < vs * 10) {
        const int s = tid / 10;
        const int t10 = tid % 10;
        const int half = t10 / 5;
        const int pg = t10 % 5;
        float pm0 = -1e30f, pm1 = -1e30f, pm2 = -1e30f, pm3 = -1e30f;
        for (int n = 0; n < 5; ++n) {
            int i, j;
            if (half == 0) { i = pg; j = 5 + n; } else { i = 5 + pg; j = n; }
            const unsigned* ur  = hX + (s * 10 + i) * 17;
            const unsigned* vrw = hX + (s * 10 + j) * 17 + 8;
            float h1p[16];
            #pragma unroll
            for (int cc = 0; cc < 8; ++cc) {
                const unsigned uu = ur[cc], vv = vrw[cc];
                h1p[2 * cc]     = fmaxf(bf_lo(uu) + bf_lo(vv) + c_b1[2 * cc], 0.f);
                h1p[2 * cc + 1] = fmaxf(bf_hi(uu) + bf_hi(vv) + c_b1[2 * cc + 1], 0.f);
            }
            float a[16];
            #pragma unroll
            for (int o = 0; o < 16; ++o) a[o] = c_b2[o];
            #pragma unroll
            for (int k = 0; k < 16; ++k) {
                const float hk = h1p[k];
                const float* wr = c_w2 + k * 16;
                #pragma unroll
                for (int o = 0; o < 16; ++o) a[o] = fmaf(hk, wr[o], a[o]);
            }
            float c3[8];
            #pragma unroll
            for (int o = 0; o < 8; ++o) c3[o] = c_b3[o];
            #pragma unroll
            for (int k = 0; k < 16; ++k) {
                const float hk = fmaxf(a[k], 0.f);
                const float* wr = c_w3 + k * 8;
                #pragma unroll
                for (int o = 0; o < 8; ++o) c3[o] = fmaf(hk, wr[o], c3[o]);
            }
            pm0 = fmaxf(pm0, fmaxf(c3[0], c3[1]));
            pm1 = fmaxf(pm1, fmaxf(c3[2], c3[3]));
            pm2 = fmaxf(pm2, fmaxf(c3[4], c3[5]));
            pm3 = fmaxf(pm3, fmaxf(c3[6], c3[7]));
        }
        float* dst = sPm + ((s * 2 + half) * 5 + pg) * 4;
        dst[0] = pm0; dst[1] = pm1; dst[2] = pm2; dst[3] = pm3;
    }
    __syncthreads();

    // ---- max over 5 groups -> g (global) ----
    if (tid < vs * 8) {
        const int s = tid >> 3;
        const int r = tid & 7;
        const int half = r >> 2, m = r & 3;
        float mx = -1e30f;
        #pragma unroll
        for (int pg = 0; pg < 5; ++pg)
            mx = fmaxf(mx, sPm[((s * 2 + half) * 5 + pg) * 4 + m]);
        g_ws[(size_t)(s0 + s) * 8 + r] = mx;
    }
}

// ================= K3: team + final MLP -> out ==================
__global__ __launch_bounds__(256, 4) void k3_team(
    const unsigned* __restrict__ ho_ws,
    const float* __restrict__ g_ws,
    const float* __restrict__ t_w1, const float* __restrict__ t_b1,
    const float* __restrict__ t_w2, const float* __restrict__ t_b2,
    const float* __restrict__ t_w3, const float* __restrict__ t_b3,
    const float* __restrict__ f_w1, const float* __restrict__ f_b1,
    const float* __restrict__ f_w2, const float* __restrict__ f_b2,
    const float* __restrict__ f_w3, const float* __restrict__ f_b3,
    float* __restrict__ out)
{
    // [0,2880) ho32 [320][9]u32 (stage..E1) -> h2t [64][33]=2112 (E2..E3)
    // [2880,3136) sG 256 f32
    // [3136,5248) h1t [64][33] (E1..E2) -> sT f32 [32][33]=1056 (E3..F)
    __shared__ unsigned smem_u[5248];
    unsigned* const ho32 = smem_u;
    unsigned* const h2t  = smem_u;
    float*    const sG   = (float*)(smem_u + 2880);
    unsigned* const h1t  = smem_u + 3136;
    float*    const sT   = (float*)(smem_u + 3136);

    const int tid = threadIdx.x;
    const int s0  = blockIdx.x * SPB3;
    const int vs  = (NB - s0 < SPB3) ? (NB - s0) : SPB3;
    const int vr  = vs * 10;

    // stage ho + g
    for (int j = tid; j < vr * 8; j += 256) {
        const int row = j >> 3, q = j & 7;
        ho32[row * 9 + q] = ho_ws[((size_t)s0 * 10 + row) * 8 + q];
    }
    for (int j = tid; j < vs * 8; j += 256)
        sG[j] = g_ws[(size_t)s0 * 8 + j];
    __syncthreads();

    // E1: team layer 1 (84->64), 4 lanes/row, 64 rows
    if (tid < vs * 8) {
        const int s = tid >> 3;
        const int half = (tid >> 2) & 1;
        const int q = tid & 3;
        const int oq = q * 16;
        float a[16];
        #pragma unroll
        for (int o = 0; o < 16; ++o) a[o] = t_b1[oq + o];
        for (int h5 = 0; h5 < 5; ++h5) {
            const int row = s * 10 + half * 5 + h5;
            #pragma unroll
            for (int cc = 0; cc < 8; ++cc) {
                const unsigned hv = ho32[row * 9 + cc];
                const float x0 = bf_lo(hv), x1 = bf_hi(hv);
                const int k0 = h5 * 16 + 2 * cc;
                #pragma unroll
                for (int ob = 0; ob < 4; ++ob) {
                    const float4 w0 = *(const float4*)(t_w1 + k0 * 64 + oq + ob * 4);
                    const float4 w1 = *(const float4*)(t_w1 + (k0 + 1) * 64 + oq + ob * 4);
                    a[ob * 4 + 0] = fmaf(x0, w0.x, a[ob * 4 + 0]);
                    a[ob * 4 + 1] = fmaf(x0, w0.y, a[ob * 4 + 1]);
                    a[ob * 4 + 2] = fmaf(x0, w0.z, a[ob * 4 + 2]);
                    a[ob * 4 + 3] = fmaf(x0, w0.w, a[ob * 4 + 3]);
                    a[ob * 4 + 0] = fmaf(x1, w1.x, a[ob * 4 + 0]);
                    a[ob * 4 + 1] = fmaf(x1, w1.y, a[ob * 4 + 1]);
                    a[ob * 4 + 2] = fmaf(x1, w1.z, a[ob * 4 + 2]);
                    a[ob * 4 + 3] = fmaf(x1, w1.w, a[ob * 4 + 3]);
                }
            }
        }
        #pragma unroll
        for (int m = 0; m < 4; ++m) {
            const float gv = sG[s * 8 + half * 4 + m];
            #pragma unroll
            for (int ob = 0; ob < 4; ++ob) {
                const float4 w = *(const float4*)(t_w1 + (80 + m) * 64 + oq + ob * 4);
                a[ob * 4 + 0] = fmaf(gv, w.x, a[ob * 4 + 0]);
                a[ob * 4 + 1] = fmaf(gv, w.y, a[ob * 4 + 1]);
                a[ob * 4 + 2] = fmaf(gv, w.z, a[ob * 4 + 2]);
                a[ob * 4 + 3] = fmaf(gv, w.w, a[ob * 4 + 3]);
            }
        }
        const int row2 = s * 2 + half;
        #pragma unroll
        for (int cc = 0; cc < 8; ++cc)
            h1t[row2 * 33 + q * 8 + cc] =
                pack_bf(fmaxf(a[2 * cc], 0.f), fmaxf(a[2 * cc + 1], 0.f));
    }
    __syncthreads();

    // E2: team layer 2 (64->64); writes h2t over dead ho region
    if (tid < vs * 8) {
        const int s = tid >> 3;
        const int half = (tid >> 2) & 1;
        const int q = tid & 3;
        const int oq = q * 16;
        const int row2 = s * 2 + half;
        float a[16];
        #pragma unroll
        for (int o = 0; o < 16; ++o) a[o] = t_b2[oq + o];
        #pragma unroll 8
        for (int cc = 0; cc < 32; ++cc) {
            const unsigned hv = h1t[row2 * 33 + cc];
            const float x0 = bf_lo(hv), x1 = bf_hi(hv);
            #pragma unroll
            for (int ob = 0; ob < 4; ++ob) {
                const float4 w0 = *(const float4*)(t_w2 + (2 * cc) * 64 + oq + ob * 4);
                const float4 w1 = *(const float4*)(t_w2 + (2 * cc + 1) * 64 + oq + ob * 4);
                a[ob * 4 + 0] = fmaf(x0, w0.x, a[ob * 4 + 0]);
                a[ob * 4 + 1] = fmaf(x0, w0.y, a[ob * 4 + 1]);
                a[ob * 4 + 2] = fmaf(x0, w0.z, a[ob * 4 + 2]);
                a[ob * 4 + 3] = fmaf(x0, w0.w, a[ob * 4 + 3]);
                a[ob * 4 + 0] = fmaf(x1, w1.x, a[ob * 4 + 0]);
                a[ob * 4 + 1] = fmaf(x1, w1.y, a[ob * 4 + 1]);
                a[ob * 4 + 2] = fmaf(x1, w1.z, a[ob * 4 + 2]);
                a[ob * 4 + 3] = fmaf(x1, w1.w, a[ob * 4 + 3]);
            }
        }
        __syncthreads();              // h1t reads done; ho region reusable
        #pragma unroll
        for (int cc = 0; cc < 8; ++cc)
            h2t[row2 * 33 + q * 8 + cc] =
                pack_bf(fmaxf(a[2 * cc], 0.f), fmaxf(a[2 * cc + 1], 0.f));
    } else {
        __syncthreads();
    }
    __syncthreads();

    // E3: team layer 3 (64->16, linear); writes sT over dead h1t
    if (tid < vs * 8) {
        const int s = tid >> 3;
        const int half = (tid >> 2) & 1;
        const int q = tid & 3;
        const int oq = q * 4;
        const int row2 = s * 2 + half;
        float a0s = t_b3[oq], a1s = t_b3[oq + 1], a2s = t_b3[oq + 2], a3s = t_b3[oq + 3];
        #pragma unroll 8
        for (int cc = 0; cc < 32; ++cc) {
            const unsigned hv = h2t[row2 * 33 + cc];
            const float x0 = bf_lo(hv), x1 = bf_hi(hv);
            const float4 w0 = *(const float4*)(t_w3 + (2 * cc) * 16 + oq);
            const float4 w1 = *(const float4*)(t_w3 + (2 * cc + 1) * 16 + oq);
            a0s = fmaf(x0, w0.x, a0s); a1s = fmaf(x0, w0.y, a1s);
            a2s = fmaf(x0, w0.z, a2s); a3s = fmaf(x0, w0.w, a3s);
            a0s = fmaf(x1, w1.x, a0s); a1s = fmaf(x1, w1.y, a1s);
            a2s = fmaf(x1, w1.z, a2s); a3s = fmaf(x1, w1.w, a3s);
        }
        __syncthreads();              // h1t reads done (sT aliases h1t)
        float* dst = sT + s * 33 + half * 16 + oq;
        dst[0] = a0s; dst[1] = a1s; dst[2] = a2s; dst[3] = a3s;
    } else {
        __syncthreads();
    }
    __syncthreads();

    // F: final MLP (32->16->16->2) + softmax, 1 lane/sample
    if (tid < vs) {
        const float* tr = sT + tid * 33;
        float g1[16];
        #pragma unroll
        for (int o = 0; o < 16; ++o) g1[o] = f_b1[o];
        #pragma unroll
        for (int k = 0; k < 32; ++k) {
            const float hk = tr[k];
            const float* wr = f_w1 + k * 16;
            #pragma unroll
            for (int o = 0; o < 16; ++o) g1[o] = fmaf(hk, wr[o], g1[o]);
        }
        float g2[16];
        #pragma unroll
        for (int o = 0; o < 16; ++o) g2[o] = f_b2[o];
        #pragma unroll
        for (int k = 0; k < 16; ++k) {
            const float hk = fmaxf(g1[k], 0.f);
            const float* wr = f_w2 + k * 16;
            #pragma unroll
            for (int o = 0; o < 16; ++o) g2[o] = fmaf(hk, wr[o], g2[o]);
        }
        float l0 = f_b3[0], l1 = f_b3[1];
        #pragma unroll
        for (int k = 0; k < 16; ++k) {
            const float hk = fmaxf(g2[k], 0.f);
            l0 = fmaf(hk, f_w3[2 * k], l0);
            l1 = fmaf(hk, f_w3[2 * k + 1], l1);
        }
        const float e = expf(l1 - l0);
        const float p0 = 1.f / (1.f + e);
        out[(size_t)(s0 + tid) * 2]     = p0;
        out[(size_t)(s0 + tid) * 2 + 1] = 1.f - p0;
    }
}

extern "C" void kernel_launch(void* const* d_in, const int* in_sizes, int n_in,
                              void* d_out, int out_size, void* d_ws, size_t ws_size,
                              hipStream_t stream) {
    (void)in_sizes; (void)n_in; (void)out_size; (void)ws_size;
    const float* x    = (const float*)d_in[0];
    const float* h_w1 = (const float*)d_in[1];  const float* h_b1 = (const float*)d_in[2];
    const float* h_w2 = (const float*)d_in[3];  const float* h_b2 = (const float*)d_in[4];
    const float* h_w3 = (const float*)d_in[5];  const float* h_b3 = (const float*)d_in[6];
    const float* c_w1 = (const float*)d_in[7];  const float* c_b1 = (const float*)d_in[8];
    const float* c_w2 = (const float*)d_in[9];  const float* c_b2 = (const float*)d_in[10];
    const float* c_w3 = (const float*)d_in[11]; const float* c_b3 = (const float*)d_in[12];
    const float* t_w1 = (const float*)d_in[13]; const float* t_b1 = (const float*)d_in[14];
    const float* t_w2 = (const float*)d_in[15]; const float* t_b2 = (const float*)d_in[16];
    const float* t_w3 = (const float*)d_in[17]; const float* t_b3 = (const float*)d_in[18];
    const float* f_w1 = (const float*)d_in[19]; const float* f_b1 = (const float*)d_in[20];
    const float* f_w2 = (const float*)d_in[21]; const float* f_b2 = (const float*)d_in[22];
    const float* f_w3 = (const float*)d_in[23]; const float* f_b3 = (const float*)d_in[24];
    float* out = (float*)d_out;

    // ws layout: ho [NB*10*8 u32] = 20.97MB, then g [NB*8 f32] = 2.10MB
    unsigned* ho_ws = (unsigned*)d_ws;
    float*    g_ws  = (float*)((char*)d_ws + (size_t)NB * 10 * 8 * 4);

    const int grid12 = (NB + SPB - 1) / SPB;    // 2731
    const int grid3  = NB / SPB3;               // 2048

    k1_hero<<<grid12, 256, 0, stream>>>(x, h_w1, h_b1, h_w2, h_b2, h_w3, h_b3, ho_ws);
    k2_counter<<<grid12, 256, 0, stream>>>(ho_ws, c_w1, c_b1, c_w2, c_b2, c_w3, c_b3, g_ws);
    k3_team<<<grid3, 256, 0, stream>>>(ho_ws, g_ws,
        t_w1, t_b1, t_w2, t_b2, t_w3, t_b3,
        f_w1, f_b1, f_w2, f_b2, f_w3, f_b3, out);
}

// Round 15
// 272.138 us; speedup vs baseline: 1.8502x; 1.8502x over previous
//
#include <hip/hip_runtime.h>
#include <hip/hip_bf16.h>
#include <math.h>

// Round 15: MFMA the team MLP (k3 was 292us of the 503 -- latency-bound on
// per-lane weight loads, VALUBusy 9.5%). k3 rewritten: stage team input
// [64][96]bf16 in LDS (stride 104 u16, 2-way banks), JIT B-frags, wave-
// private 16-row tiles -> barrier-free L1->L2->L3 chain. K1/K2 unchanged.

#define NB 65536
#define SPB 24          // K1/K2
#define SPB3 32         // K3 (NB % 32 == 0 -> always-full blocks)

typedef __attribute__((ext_vector_type(8))) short short8;
typedef __attribute__((ext_vector_type(4))) float f32x4;

__device__ __forceinline__ unsigned bfr(float f) {
    unsigned u = __float_as_uint(f);
    return (u + 0x7fffu + ((u >> 16) & 1u)) >> 16;
}
__device__ __forceinline__ unsigned pack_bf(float a, float b) {
    return bfr(a) | (bfr(b) << 16);
}
__device__ __forceinline__ float bf_lo(unsigned u) { return __uint_as_float(u << 16); }
__device__ __forceinline__ float bf_hi(unsigned u) { return __uint_as_float(u & 0xffff0000u); }

// ================= K1: hero chain (140->32->32->16), MFMA ==================
__global__ __launch_bounds__(256, 4) void k1_hero(
    const float* __restrict__ x,
    const float* __restrict__ h_w1, const float* __restrict__ h_b1,
    const float* __restrict__ h_w2, const float* __restrict__ h_b2,
    const float* __restrict__ h_w3, const float* __restrict__ h_b3,
    unsigned* __restrict__ ho_ws)      // [NB*10][8] u32 (16 bf16/row)
{
    __shared__ unsigned smem_u[4800];            // 19.2 KB: acts [240][40] u16
    unsigned short* const acts = (unsigned short*)smem_u;

    const int tid = threadIdx.x;
    const int s0  = blockIdx.x * SPB;
    const int vs  = (NB - s0 < SPB) ? (NB - s0) : SPB;
    const int vr  = vs * 10;

    const int lane = tid & 63;
    const int wv   = tid >> 6;
    const int lm   = lane & 15;
    const int lg   = lane >> 4;
    const short8 zero8 = (short8){0,0,0,0,0,0,0,0};

    // ---- L1: [240x140]@[140x32], rolled K-chunks, JIT B-frags ----
    f32x4 acc[4][2];
    #pragma unroll
    for (int t = 0; t < 4; ++t) {
        const float b0 = h_b1[lm], b1 = h_b1[16 + lm];
        acc[t][0] = (f32x4){b0, b0, b0, b0};
        acc[t][1] = (f32x4){b1, b1, b1, b1};
    }
    for (int c = 0; c < 5; ++c) {
        short8 w0f, w1f;
        #pragma unroll
        for (int i = 0; i < 8; ++i) {
            const int k = c * 32 + lg * 8 + i;
            w0f[i] = (short)((k < 140) ? bfr(h_w1[k * 32 + lm]) : 0);
            w1f[i] = (short)((k < 140) ? bfr(h_w1[k * 32 + 16 + lm]) : 0);
        }
        for (int j = tid; j < vr * 8; j += 256) {
            const int row = j >> 3, q = j & 7;
            unsigned lo = 0, hi = 0;
            if (c < 4 || q < 3) {
                const float4 v = *(const float4*)(
                    x + ((size_t)s0 * 10 + row) * 140 + c * 32 + q * 4);
                lo = pack_bf(v.x, v.y);
                hi = pack_bf(v.z, v.w);
            }
            smem_u[row * 20 + q * 2]     = lo;
            smem_u[row * 20 + q * 2 + 1] = hi;
        }
        __syncthreads();
        #pragma unroll
        for (int t = 0; t < 4; ++t) {
            const int tl = wv + 4 * t;
            if (tl < 15) {
                const short8 af = *(const short8*)(acts + (tl * 16 + lm) * 40 + lg * 8);
                acc[t][0] = __builtin_amdgcn_mfma_f32_16x16x32_bf16(af, w0f, acc[t][0], 0, 0, 0);
                acc[t][1] = __builtin_amdgcn_mfma_f32_16x16x32_bf16(af, w1f, acc[t][1], 0, 0, 0);
            }
        }
        __syncthreads();
    }
    #pragma unroll
    for (int t = 0; t < 4; ++t) {
        const int tl = wv + 4 * t;
        if (tl < 15) {
            #pragma unroll
            for (int nt = 0; nt < 2; ++nt)
                #pragma unroll
                for (int r = 0; r < 4; ++r)
                    acts[(tl * 16 + lg * 4 + r) * 40 + nt * 16 + lm] =
                        (unsigned short)bfr(fmaxf(acc[t][nt][r], 0.f));
        }
    }
    __syncthreads();

    // ---- L2: [240x32]@[32x32], in-place ----
    {
        short8 af[4];
        #pragma unroll
        for (int t = 0; t < 4; ++t) {
            const int tl = wv + 4 * t;
            af[t] = (tl < 15) ? *(const short8*)(acts + (tl * 16 + lm) * 40 + lg * 8) : zero8;
        }
        short8 w0f, w1f;
        #pragma unroll
        for (int i = 0; i < 8; ++i) {
            const int k = lg * 8 + i;
            w0f[i] = (short)bfr(h_w2[k * 32 + lm]);
            w1f[i] = (short)bfr(h_w2[k * 32 + 16 + lm]);
        }
        __syncthreads();
        #pragma unroll
        for (int t = 0; t < 4; ++t) {
            const float b0 = h_b2[lm], b1 = h_b2[16 + lm];
            f32x4 a20 = (f32x4){b0, b0, b0, b0};
            f32x4 a21 = (f32x4){b1, b1, b1, b1};
            const int tl = wv + 4 * t;
            if (tl < 15) {
                a20 = __builtin_amdgcn_mfma_f32_16x16x32_bf16(af[t], w0f, a20, 0, 0, 0);
                a21 = __builtin_amdgcn_mfma_f32_16x16x32_bf16(af[t], w1f, a21, 0, 0, 0);
                #pragma unroll
                for (int r = 0; r < 4; ++r) {
                    acts[(tl * 16 + lg * 4 + r) * 40 + lm]      =
                        (unsigned short)bfr(fmaxf(a20[r], 0.f));
                    acts[(tl * 16 + lg * 4 + r) * 40 + 16 + lm] =
                        (unsigned short)bfr(fmaxf(a21[r], 0.f));
                }
            }
        }
        __syncthreads();
    }

    // ---- L3: [240x32]@[32x16] (linear) -> acts cols 0..15 ----
    {
        short8 af[4];
        #pragma unroll
        for (int t = 0; t < 4; ++t) {
            const int tl = wv + 4 * t;
            af[t] = (tl < 15) ? *(const short8*)(acts + (tl * 16 + lm) * 40 + lg * 8) : zero8;
        }
        short8 w3f;
        #pragma unroll
        for (int i = 0; i < 8; ++i)
            w3f[i] = (short)bfr(h_w3[(lg * 8 + i) * 16 + lm]);
        __syncthreads();
        #pragma unroll
        for (int t = 0; t < 4; ++t) {
            const float b = h_b3[lm];
            f32x4 a3 = (f32x4){b, b, b, b};
            const int tl = wv + 4 * t;
            if (tl < 15) {
                a3 = __builtin_amdgcn_mfma_f32_16x16x32_bf16(af[t], w3f, a3, 0, 0, 0);
                #pragma unroll
                for (int r = 0; r < 4; ++r)
                    acts[(tl * 16 + lg * 4 + r) * 40 + lm] = (unsigned short)bfr(a3[r]);
            }
        }
        __syncthreads();
    }

    // ---- coalesced ho writeback: [vr][8] u32 ----
    for (int j = tid; j < vr * 8; j += 256) {
        const int row = j >> 3, q = j & 7;
        ho_ws[((size_t)s0 * 10 + row) * 8 + q] = smem_u[row * 20 + q];
    }
}

// ================= K2: uv + counter pairs + pool -> g ==================
__global__ __launch_bounds__(256, 4) void k2_counter(
    const unsigned* __restrict__ ho_ws,
    const float* __restrict__ c_w1, const float* __restrict__ c_b1,
    const float* __restrict__ c_w2, const float* __restrict__ c_b2,
    const float* __restrict__ c_w3, const float* __restrict__ c_b3,
    float* __restrict__ g_ws)          // [NB][8] f32
{
    __shared__ unsigned smem_u[5040];  // hX [240][17]=4080 | sPm 960 f32
    unsigned* const hX  = smem_u;
    float*    const sPm = (float*)(smem_u + 4080);

    const int tid = threadIdx.x;
    const int s0  = blockIdx.x * SPB;
    const int vs  = (NB - s0 < SPB) ? (NB - s0) : SPB;
    const int vr  = vs * 10;

    if (tid < vr) {
        const uint4 p0 = *(const uint4*)(ho_ws + ((size_t)s0 * 10 + tid) * 8);
        const uint4 p1 = *(const uint4*)(ho_ws + ((size_t)s0 * 10 + tid) * 8 + 4);
        float ho[16];
        ho[0] = bf_lo(p0.x); ho[1] = bf_hi(p0.x); ho[2] = bf_lo(p0.y); ho[3] = bf_hi(p0.y);
        ho[4] = bf_lo(p0.z); ho[5] = bf_hi(p0.z); ho[6] = bf_lo(p0.w); ho[7] = bf_hi(p0.w);
        ho[8] = bf_lo(p1.x); ho[9] = bf_hi(p1.x); ho[10] = bf_lo(p1.y); ho[11] = bf_hi(p1.y);
        ho[12] = bf_lo(p1.z); ho[13] = bf_hi(p1.z); ho[14] = bf_lo(p1.w); ho[15] = bf_hi(p1.w);
        float u[16], v[16];
        #pragma unroll
        for (int o = 0; o < 16; ++o) { u[o] = 0.f; v[o] = 0.f; }
        #pragma unroll
        for (int k = 0; k < 16; ++k) {
            const float hk = ho[k];
            const float* wu = c_w1 + k * 16;
            const float* wv = c_w1 + (16 + k) * 16;
            #pragma unroll
            for (int o = 0; o < 16; ++o) {
                u[o] = fmaf(hk, wu[o], u[o]);
                v[o] = fmaf(hk, wv[o], v[o]);
            }
        }
        #pragma unroll
        for (int cc = 0; cc < 8; ++cc) {
            hX[tid * 17 + cc]     = pack_bf(u[2 * cc], u[2 * cc + 1]);
            hX[tid * 17 + 8 + cc] = pack_bf(v[2 * cc], v[2 * cc + 1]);
        }
    }
    __syncthreads();

    if (tid < vs * 10) {
        const int s = tid / 10;
        const int t10 = tid % 10;
        const int half = t10 / 5;
        const int pg = t10 % 5;
        float pm0 = -1e30f, pm1 = -1e30f, pm2 = -1e30f, pm3 = -1e30f;
        for (int n = 0; n < 5; ++n) {
            int i, j;
            if (half == 0) { i = pg; j = 5 + n; } else { i = 5 + pg; j = n; }
            const unsigned* ur  = hX + (s * 10 + i) * 17;
            const unsigned* vrw = hX + (s * 10 + j) * 17 + 8;
            float h1p[16];
            #pragma unroll
            for (int cc = 0; cc < 8; ++cc) {
                const unsigned uu = ur[cc], vv = vrw[cc];
                h1p[2 * cc]     = fmaxf(bf_lo(uu) + bf_lo(vv) + c_b1[2 * cc], 0.f);
                h1p[2 * cc + 1] = fmaxf(bf_hi(uu) + bf_hi(vv) + c_b1[2 * cc + 1], 0.f);
            }
            float a[16];
            #pragma unroll
            for (int o = 0; o < 16; ++o) a[o] = c_b2[o];
            #pragma unroll
            for (int k = 0; k < 16; ++k) {
                const float hk = h1p[k];
                const float* wr = c_w2 + k * 16;
                #pragma unroll
                for (int o = 0; o < 16; ++o) a[o] = fmaf(hk, wr[o], a[o]);
            }
            float c3[8];
            #pragma unroll
            for (int o = 0; o < 8; ++o) c3[o] = c_b3[o];
            #pragma unroll
            for (int k = 0; k < 16; ++k) {
                const float hk = fmaxf(a[k], 0.f);
                const float* wr = c_w3 + k * 8;
                #pragma unroll
                for (int o = 0; o < 8; ++o) c3[o] = fmaf(hk, wr[o], c3[o]);
            }
            pm0 = fmaxf(pm0, fmaxf(c3[0], c3[1]));
            pm1 = fmaxf(pm1, fmaxf(c3[2], c3[3]));
            pm2 = fmaxf(pm2, fmaxf(c3[4], c3[5]));
            pm3 = fmaxf(pm3, fmaxf(c3[6], c3[7]));
        }
        float* dst = sPm + ((s * 2 + half) * 5 + pg) * 4;
        dst[0] = pm0; dst[1] = pm1; dst[2] = pm2; dst[3] = pm3;
    }
    __syncthreads();

    if (tid < vs * 8) {
        const int s = tid >> 3;
        const int r = tid & 7;
        const int half = r >> 2, m = r & 3;
        float mx = -1e30f;
        #pragma unroll
        for (int pg = 0; pg < 5; ++pg)
            mx = fmaxf(mx, sPm[((s * 2 + half) * 5 + pg) * 4 + m]);
        g_ws[(size_t)(s0 + s) * 8 + r] = mx;
    }
}

// ================= K3: team (MFMA) + final MLP -> out ==================
__global__ __launch_bounds__(256, 4) void k3_team(
    const unsigned* __restrict__ ho_ws,
    const float* __restrict__ g_ws,
    const float* __restrict__ t_w1, const float* __restrict__ t_b1,
    const float* __restrict__ t_w2, const float* __restrict__ t_b2,
    const float* __restrict__ t_w3, const float* __restrict__ t_b3,
    const float* __restrict__ f_w1, const float* __restrict__ f_b1,
    const float* __restrict__ f_w2, const float* __restrict__ f_b2,
    const float* __restrict__ f_w3, const float* __restrict__ f_b3,
    float* __restrict__ out)
{
    // LDS: acts u32 [64][52] (rows stride 104 u16; cols 0..83 data, 84..95 0)
    //      sT f32 [32][33]
    __shared__ unsigned smem_u[3328 + 1056];
    unsigned* const acts = smem_u;
    unsigned short* const aU = (unsigned short*)smem_u;
    float* const sT = (float*)(smem_u + 3328);

    const int tid = threadIdx.x;
    const int s0  = blockIdx.x * SPB3;    // always-full blocks (NB%32==0)

    const int lane = tid & 63;
    const int wv   = tid >> 6;            // wave owns rows wv*16..wv*16+15
    const int lm   = lane & 15;
    const int lg   = lane >> 4;

    // ---- stage team input: row r(=s*2+half): 80 bf16 ho | 4 g | 12 zero ----
    for (int j = tid; j < 64 * 52; j += 256) {
        const int row = j / 52, q = j % 52;
        const int s = row >> 1, half = row & 1;
        unsigned val = 0;
        if (q < 40) {
            const int hh = q >> 3, qq = q & 7;
            val = ho_ws[((size_t)(s0 + s) * 10 + half * 5 + hh) * 8 + qq];
        } else if (q < 42) {
            const float* gp = g_ws + (size_t)(s0 + s) * 8 + half * 4 + (q - 40) * 2;
            val = pack_bf(gp[0], gp[1]);
        }
        acts[row * 52 + q] = val;
    }
    __syncthreads();

    // ---- team L1: [64x84]@[84x64], K padded to 96 (3 chunks) ----
    f32x4 a1[4];
    #pragma unroll
    for (int nt = 0; nt < 4; ++nt) {
        const float b = t_b1[nt * 16 + lm];
        a1[nt] = (f32x4){b, b, b, b};
    }
    for (int c = 0; c < 3; ++c) {
        const short8 af = *(const short8*)(aU + (wv * 16 + lm) * 104 + c * 32 + lg * 8);
        #pragma unroll
        for (int nt = 0; nt < 4; ++nt) {
            short8 wf;
            #pragma unroll
            for (int i = 0; i < 8; ++i) {
                const int k = c * 32 + lg * 8 + i;
                wf[i] = (short)((k < 84) ? bfr(t_w1[k * 64 + nt * 16 + lm]) : 0);
            }
            a1[nt] = __builtin_amdgcn_mfma_f32_16x16x32_bf16(af, wf, a1[nt], 0, 0, 0);
        }
    }
    // relu -> in-place (wave-private rows; DS ops in-order per wave)
    #pragma unroll
    for (int nt = 0; nt < 4; ++nt)
        #pragma unroll
        for (int r = 0; r < 4; ++r)
            aU[(wv * 16 + lg * 4 + r) * 104 + nt * 16 + lm] =
                (unsigned short)bfr(fmaxf(a1[nt][r], 0.f));

    // ---- team L2: [64x64]@[64x64], 2 chunks ----
    f32x4 a2[4];
    #pragma unroll
    for (int nt = 0; nt < 4; ++nt) {
        const float b = t_b2[nt * 16 + lm];
        a2[nt] = (f32x4){b, b, b, b};
    }
    for (int c = 0; c < 2; ++c) {
        const short8 af = *(const short8*)(aU + (wv * 16 + lm) * 104 + c * 32 + lg * 8);
        #pragma unroll
        for (int nt = 0; nt < 4; ++nt) {
            short8 wf;
            #pragma unroll
            for (int i = 0; i < 8; ++i) {
                const int k = c * 32 + lg * 8 + i;
                wf[i] = (short)bfr(t_w2[k * 64 + nt * 16 + lm]);
            }
            a2[nt] = __builtin_amdgcn_mfma_f32_16x16x32_bf16(af, wf, a2[nt], 0, 0, 0);
        }
    }
    #pragma unroll
    for (int nt = 0; nt < 4; ++nt)
        #pragma unroll
        for (int r = 0; r < 4; ++r)
            aU[(wv * 16 + lg * 4 + r) * 104 + nt * 16 + lm] =
                (unsigned short)bfr(fmaxf(a2[nt][r], 0.f));

    // ---- team L3: [64x64]@[64x16] linear, 2 chunks ----
    {
        const float b = t_b3[lm];
        f32x4 a3 = (f32x4){b, b, b, b};
        for (int c = 0; c < 2; ++c) {
            const short8 af = *(const short8*)(aU + (wv * 16 + lm) * 104 + c * 32 + lg * 8);
            short8 wf;
            #pragma unroll
            for (int i = 0; i < 8; ++i) {
                const int k = c * 32 + lg * 8 + i;
                wf[i] = (short)bfr(t_w3[k * 16 + lm]);
            }
            a3 = __builtin_amdgcn_mfma_f32_16x16x32_bf16(af, wf, a3, 0, 0, 0);
        }
        #pragma unroll
        for (int r = 0; r < 4; ++r) {
            const int row = wv * 16 + lg * 4 + r;     // 0..63 = s*2+half
            sT[(row >> 1) * 33 + (row & 1) * 16 + lm] = a3[r];
        }
    }
    __syncthreads();

    // ---- F: final MLP (32->16->16->2) + softmax, 1 lane/sample ----
    if (tid < SPB3) {
        const float* tr = sT + tid * 33;
        float g1[16];
        #pragma unroll
        for (int o = 0; o < 16; ++o) g1[o] = f_b1[o];
        #pragma unroll
        for (int k = 0; k < 32; ++k) {
            const float hk = tr[k];
            const float* wr = f_w1 + k * 16;
            #pragma unroll
            for (int o = 0; o < 16; ++o) g1[o] = fmaf(hk, wr[o], g1[o]);
        }
        float g2[16];
        #pragma unroll
        for (int o = 0; o < 16; ++o) g2[o] = f_b2[o];
        #pragma unroll
        for (int k = 0; k < 16; ++k) {
            const float hk = fmaxf(g1[k], 0.f);
            const float* wr = f_w2 + k * 16;
            #pragma unroll
            for (int o = 0; o < 16; ++o) g2[o] = fmaf(hk, wr[o], g2[o]);
        }
        float l0 = f_b3[0], l1 = f_b3[1];
        #pragma unroll
        for (int k = 0; k < 16; ++k) {
            const float hk = fmaxf(g2[k], 0.f);
            l0 = fmaf(hk, f_w3[2 * k], l0);
            l1 = fmaf(hk, f_w3[2 * k + 1], l1);
        }
        const float e = expf(l1 - l0);
        const float p0 = 1.f / (1.f + e);
        out[(size_t)(s0 + tid) * 2]     = p0;
        out[(size_t)(s0 + tid) * 2 + 1] = 1.f - p0;
    }
}

extern "C" void kernel_launch(void* const* d_in, const int* in_sizes, int n_in,
                              void* d_out, int out_size, void* d_ws, size_t ws_size,
                              hipStream_t stream) {
    (void)in_sizes; (void)n_in; (void)out_size; (void)ws_size;
    const float* x    = (const float*)d_in[0];
    const float* h_w1 = (const float*)d_in[1];  const float* h_b1 = (const float*)d_in[2];
    const float* h_w2 = (const float*)d_in[3];  const float* h_b2 = (const float*)d_in[4];
    const float* h_w3 = (const float*)d_in[5];  const float* h_b3 = (const float*)d_in[6];
    const float* c_w1 = (const float*)d_in[7];  const float* c_b1 = (const float*)d_in[8];
    const float* c_w2 = (const float*)d_in[9];  const float* c_b2 = (const float*)d_in[10];
    const float* c_w3 = (const float*)d_in[11]; const float* c_b3 = (const float*)d_in[12];
    const float* t_w1 = (const float*)d_in[13]; const float* t_b1 = (const float*)d_in[14];
    const float* t_w2 = (const float*)d_in[15]; const float* t_b2 = (const float*)d_in[16];
    const float* t_w3 = (const float*)d_in[17]; const float* t_b3 = (const float*)d_in[18];
    const float* f_w1 = (const float*)d_in[19]; const float* f_b1 = (const float*)d_in[20];
    const float* f_w2 = (const float*)d_in[21]; const float* f_b2 = (const float*)d_in[22];
    const float* f_w3 = (const float*)d_in[23]; const float* f_b3 = (const float*)d_in[24];
    float* out = (float*)d_out;

    unsigned* ho_ws = (unsigned*)d_ws;
    float*    g_ws  = (float*)((char*)d_ws + (size_t)NB * 10 * 8 * 4);

    const int grid12 = (NB + SPB - 1) / SPB;    // 2731
    const int grid3  = NB / SPB3;               // 2048

    k1_hero<<<grid12, 256, 0, stream>>>(x, h_w1, h_b1, h_w2, h_b2, h_w3, h_b3, ho_ws);
    k2_counter<<<grid12, 256, 0, stream>>>(ho_ws, c_w1, c_b1, c_w2, c_b2, c_w3, c_b3, g_ws);
    k3_team<<<grid3, 256, 0, stream>>>(ho_ws, g_ws,
        t_w1, t_b1, t_w2, t_b2, t_w3, t_b3,
        f_w1, f_b1, f_w2, f_b2, f_w3, f_b3, out);
}